// Round 1
// baseline (1011.101 us; speedup 1.0000x reference)
//
#include <hip/hip_runtime.h>

static constexpr int NN = 50000;   // nodes
static constexpr int NE = 800000;  // edges
static constexpr int F  = 128;     // input features
static constexpr int H  = 64;      // hidden
static constexpr int C  = 40;      // classes

// ---------------- CSR build ----------------

__global__ __launch_bounds__(256) void k_count(const int* __restrict__ ei,
                                               int* __restrict__ deg) {
  int stride = gridDim.x * blockDim.x;
  for (int e = blockIdx.x * blockDim.x + threadIdx.x; e < NE; e += stride)
    atomicAdd(&deg[ei[NE + e]], 1);  // dst = ei[1][e]
}

// Assign each node a contiguous slot range [start, start+deg). Order across
// waves is arbitrary (one atomic per 64 nodes) -- ranges are disjoint, which
// is all the aggregation needs.
__global__ __launch_bounds__(256) void k_ranges(const int* __restrict__ deg,
                                                int* __restrict__ start,
                                                int* __restrict__ fill,
                                                int* __restrict__ counter) {
  int lane = threadIdx.x & 63;
  int wid  = (blockIdx.x * blockDim.x + threadIdx.x) >> 6;
  int nw   = (gridDim.x * blockDim.x) >> 6;
  int nchunks = (NN + 63) >> 6;
  for (int c = wid; c < nchunks; c += nw) {
    int i = (c << 6) + lane;
    int v = (i < NN) ? deg[i] : 0;
    int inc = v;
#pragma unroll
    for (int off = 1; off < 64; off <<= 1) {
      int t = __shfl_up(inc, off, 64);
      if (lane >= off) inc += t;
    }
    int total = __shfl(inc, 63, 64);
    int base = 0;
    if (lane == 63) base = atomicAdd(counter, total);
    base = __shfl(base, 63, 64);
    if (i < NN) {
      int s = base + inc - v;  // exclusive scan within wave + global base
      start[i] = s;
      fill[i]  = s;
    }
  }
}

__global__ __launch_bounds__(256) void k_fill(const int* __restrict__ ei,
                                              int* __restrict__ fill,
                                              int* __restrict__ csr_src) {
  int stride = gridDim.x * blockDim.x;
  for (int e = blockIdx.x * blockDim.x + threadIdx.x; e < NE; e += stride) {
    int pos = atomicAdd(&fill[ei[NE + e]], 1);
    csr_src[pos] = ei[e];  // src = ei[0][e]
  }
}

// ---------------- GEMM 1: p = x@Wl1, q = x@Wr1  (N x 128 -> N x 64, twice) --

__global__ __launch_bounds__(256) void k_gemm1(const float* __restrict__ x,
                                               const float* __restrict__ Wl,
                                               const float* __restrict__ Wr,
                                               float* __restrict__ p,
                                               float* __restrict__ q) {
  extern __shared__ float sW[];  // [0,8192) = Wl, [8192,16384) = Wr
  for (int i = threadIdx.x; i < F * H; i += blockDim.x) {
    sW[i]          = Wl[i];
    sW[F * H + i]  = Wr[i];
  }
  __syncthreads();
  int lane = threadIdx.x & 63;
  int wid  = (blockIdx.x * blockDim.x + threadIdx.x) >> 6;
  int nw   = (gridDim.x * blockDim.x) >> 6;
  for (int node = wid; node < NN; node += nw) {
    float xa = x[node * F + lane];        // cols 0..63
    float xb = x[node * F + 64 + lane];   // cols 64..127
    float accp = 0.f, accq = 0.f;
#pragma unroll
    for (int k = 0; k < 64; ++k) {
      float xk = __shfl(xa, k, 64);  // v_readlane broadcast
      accp += xk * sW[k * H + lane];
      accq += xk * sW[F * H + k * H + lane];
    }
#pragma unroll
    for (int k = 0; k < 64; ++k) {
      float xk = __shfl(xb, k, 64);
      accp += xk * sW[(64 + k) * H + lane];
      accq += xk * sW[F * H + (64 + k) * H + lane];
    }
    p[node * H + lane] = accp;
    q[node * H + lane] = accq;
  }
}

// ---------------- Aggregate conv1 + bias + l2norm + relu -> hidden ----------

__global__ __launch_bounds__(256) void k_agg1(const float* __restrict__ p,
                                              const float* __restrict__ q,
                                              const float* __restrict__ bl,
                                              const int* __restrict__ deg,
                                              const int* __restrict__ start,
                                              const int* __restrict__ csr_src,
                                              float* __restrict__ hidden) {
  int lane = threadIdx.x & 63;
  int wid  = (blockIdx.x * blockDim.x + threadIdx.x) >> 6;
  int nw   = (gridDim.x * blockDim.x) >> 6;
  for (int node = wid; node < NN; node += nw) {
    int d = deg[node], st = start[node];
    float acc = 0.f;
    for (int b = 0; b < d; b += 64) {
      int rem = d - b;
      int cnt = rem < 64 ? rem : 64;
      int nid = (lane < cnt) ? csr_src[st + b + lane] : 0;
      for (int t = 0; t < cnt; ++t) {
        int s = __shfl(nid, t, 64);
        acc += p[s * H + lane];  // coalesced 256B per neighbor
      }
    }
    float mean = acc / fmaxf((float)d, 1.0f);
    float v = mean + bl[lane] + q[node * H + lane];
    float ss = v * v;
#pragma unroll
    for (int off = 32; off > 0; off >>= 1) ss += __shfl_xor(ss, off, 64);
    v = v / fmaxf(sqrtf(ss), 1e-12f);
    hidden[node * H + lane] = fmaxf(v, 0.f);  // relu(l2norm(out))
  }
}

// ---------------- lin1: h = relu([x, hidden] @ Wlin + blin) -----------------

__global__ __launch_bounds__(256) void k_lin1(const float* __restrict__ x,
                                              const float* __restrict__ hidden,
                                              const float* __restrict__ W,
                                              const float* __restrict__ b,
                                              float* __restrict__ h) {
  __shared__ float sW[(F + H) * H];  // 192*64*4 = 48 KiB
  for (int i = threadIdx.x; i < (F + H) * H; i += blockDim.x) sW[i] = W[i];
  __syncthreads();
  int lane = threadIdx.x & 63;
  int wid  = (blockIdx.x * blockDim.x + threadIdx.x) >> 6;
  int nw   = (gridDim.x * blockDim.x) >> 6;
  for (int node = wid; node < NN; node += nw) {
    float xa = x[node * F + lane];
    float xb = x[node * F + 64 + lane];
    float hv = hidden[node * H + lane];
    float acc = 0.f;
#pragma unroll
    for (int k = 0; k < 64; ++k)
      acc += __shfl(xa, k, 64) * sW[k * H + lane];
#pragma unroll
    for (int k = 0; k < 64; ++k)
      acc += __shfl(xb, k, 64) * sW[(64 + k) * H + lane];
#pragma unroll
    for (int k = 0; k < 64; ++k)
      acc += __shfl(hv, k, 64) * sW[(128 + k) * H + lane];
    h[node * H + lane] = fmaxf(acc + b[lane], 0.f);
  }
}

// ---------------- GEMM 2: p2 = h@Wl2, q2 = h@Wr2  (N x 64 -> N x 40) --------

__global__ __launch_bounds__(256) void k_gemm2(const float* __restrict__ h,
                                               const float* __restrict__ Wl,
                                               const float* __restrict__ Wr,
                                               float* __restrict__ p2,
                                               float* __restrict__ q2) {
  __shared__ float sW[2 * H * C];  // 2*64*40*4 = 20 KiB
  for (int i = threadIdx.x; i < H * C; i += blockDim.x) {
    sW[i]         = Wl[i];
    sW[H * C + i] = Wr[i];
  }
  __syncthreads();
  int lane = threadIdx.x & 63;
  int wid  = (blockIdx.x * blockDim.x + threadIdx.x) >> 6;
  int nw   = (gridDim.x * blockDim.x) >> 6;
  int jl = lane < C ? lane : 0;  // clamp for lanes 40..63 (results masked)
  for (int node = wid; node < NN; node += nw) {
    float hv = h[node * H + lane];
    float accp = 0.f, accq = 0.f;
#pragma unroll
    for (int k = 0; k < 64; ++k) {
      float hk = __shfl(hv, k, 64);
      accp += hk * sW[k * C + jl];
      accq += hk * sW[H * C + k * C + jl];
    }
    if (lane < C) {
      p2[node * C + lane] = accp;
      q2[node * C + lane] = accq;
    }
  }
}

// ---------------- Aggregate conv2 + bias + l2norm -> out --------------------

__global__ __launch_bounds__(256) void k_agg2(const float* __restrict__ p2,
                                              const float* __restrict__ q2,
                                              const float* __restrict__ bl,
                                              const int* __restrict__ deg,
                                              const int* __restrict__ start,
                                              const int* __restrict__ csr_src,
                                              float* __restrict__ out) {
  int lane = threadIdx.x & 63;
  int wid  = (blockIdx.x * blockDim.x + threadIdx.x) >> 6;
  int nw   = (gridDim.x * blockDim.x) >> 6;
  for (int node = wid; node < NN; node += nw) {
    int d = deg[node], st = start[node];
    float acc = 0.f;
    for (int b = 0; b < d; b += 64) {
      int rem = d - b;
      int cnt = rem < 64 ? rem : 64;
      int nid = (lane < cnt) ? csr_src[st + b + lane] : 0;
      for (int t = 0; t < cnt; ++t) {
        int s = __shfl(nid, t, 64);
        if (lane < C) acc += p2[s * C + lane];
      }
    }
    float mean = acc / fmaxf((float)d, 1.0f);
    float v = 0.f;
    if (lane < C) v = mean + bl[lane] + q2[node * C + lane];
    float ss = v * v;
#pragma unroll
    for (int off = 32; off > 0; off >>= 1) ss += __shfl_xor(ss, off, 64);
    v = v / fmaxf(sqrtf(ss), 1e-12f);
    if (lane < C) out[node * C + lane] = v;  // no relu on final layer
  }
}

// ---------------- launch ----------------------------------------------------

static inline size_t align256(size_t x) { return (x + 255) & ~(size_t)255; }

extern "C" void kernel_launch(void* const* d_in, const int* in_sizes, int n_in,
                              void* d_out, int out_size, void* d_ws, size_t ws_size,
                              hipStream_t stream) {
  const float* x    = (const float*)d_in[0];
  const int*   ei   = (const int*)d_in[1];   // [2, E] flat: [0,E)=src, [E,2E)=dst
  const float* Wl1  = (const float*)d_in[2];
  const float* bl1  = (const float*)d_in[3];
  const float* Wr1  = (const float*)d_in[4];
  const float* Wlin = (const float*)d_in[5];
  const float* blin = (const float*)d_in[6];
  const float* Wl2  = (const float*)d_in[7];
  const float* bl2  = (const float*)d_in[8];
  const float* Wr2  = (const float*)d_in[9];
  float* out = (float*)d_out;

  // Workspace carve-up (all offsets 256B-aligned). Peak live set:
  //   K5: bufA=p1, bufB=q1, bufC=hidden | K6: bufC=hidden -> writes bufA=h
  //   K7: reads bufA=h -> writes bufB=p2, bufC=q2 | K8: reads bufB,bufC
  char* w = (char*)d_ws;
  size_t off = 0;
  int* deg     = (int*)(w + off); off += align256((size_t)NN * 4);
  int* start   = (int*)(w + off); off += align256((size_t)NN * 4);
  int* fill    = (int*)(w + off); off += align256((size_t)NN * 4);
  int* counter = (int*)(w + off); off += 256;
  int* csr_src = (int*)(w + off); off += align256((size_t)NE * 4);
  float* bufA  = (float*)(w + off); off += align256((size_t)NN * H * 4);
  float* bufB  = (float*)(w + off); off += align256((size_t)NN * H * 4);
  float* bufC  = (float*)(w + off); off += align256((size_t)NN * H * 4);

  hipMemsetAsync(deg, 0, (size_t)NN * 4, stream);
  hipMemsetAsync(counter, 0, 4, stream);

  const int T = 256;
  k_count <<<512,  T, 0, stream>>>(ei, deg);
  k_ranges<<<128,  T, 0, stream>>>(deg, start, fill, counter);
  k_fill  <<<512,  T, 0, stream>>>(ei, fill, csr_src);

  // p1 -> bufA, q1 -> bufB
  k_gemm1 <<<512,  T, 65536, stream>>>(x, Wl1, Wr1, bufA, bufB);
  // hidden -> bufC
  k_agg1  <<<1024, T, 0, stream>>>(bufA, bufB, bl1, deg, start, csr_src, bufC);
  // h -> bufA (p1 dead)
  k_lin1  <<<768,  T, 0, stream>>>(x, bufC, Wlin, blin, bufA);
  // p2 -> bufB, q2 -> bufC (q1, hidden dead)
  k_gemm2 <<<1024, T, 0, stream>>>(bufA, Wl2, Wr2, bufB, bufC);
  // out
  k_agg2  <<<1024, T, 0, stream>>>(bufB, bufC, bl2, deg, start, csr_src, out);
}

// Round 2
// 662.223 us; speedup vs baseline: 1.5268x; 1.5268x over previous
//
#include <hip/hip_runtime.h>

static constexpr int NN = 50000;   // nodes
static constexpr int NE = 800000;  // edges
static constexpr int F  = 128;     // input features
static constexpr int H  = 64;      // hidden
static constexpr int C  = 40;      // classes

// ---------------- CSR build ----------------

__global__ __launch_bounds__(256) void k_count(const int* __restrict__ ei,
                                               int* __restrict__ deg) {
  int stride = gridDim.x * blockDim.x;
  for (int e = blockIdx.x * blockDim.x + threadIdx.x; e < NE; e += stride)
    atomicAdd(&deg[ei[NE + e]], 1);  // dst = ei[1][e]
}

__global__ __launch_bounds__(256) void k_ranges(const int* __restrict__ deg,
                                                int* __restrict__ start,
                                                int* __restrict__ fill,
                                                int* __restrict__ counter) {
  int lane = threadIdx.x & 63;
  int wid  = (blockIdx.x * blockDim.x + threadIdx.x) >> 6;
  int nw   = (gridDim.x * blockDim.x) >> 6;
  int nchunks = (NN + 63) >> 6;
  for (int c = wid; c < nchunks; c += nw) {
    int i = (c << 6) + lane;
    int v = (i < NN) ? deg[i] : 0;
    int inc = v;
#pragma unroll
    for (int off = 1; off < 64; off <<= 1) {
      int t = __shfl_up(inc, off, 64);
      if (lane >= off) inc += t;
    }
    int total = __shfl(inc, 63, 64);
    int base = 0;
    if (lane == 63) base = atomicAdd(counter, total);
    base = __shfl(base, 63, 64);
    if (i < NN) {
      int s = base + inc - v;
      start[i] = s;
      fill[i]  = s;
    }
  }
}

__global__ __launch_bounds__(256) void k_fill(const int* __restrict__ ei,
                                              int* __restrict__ fill,
                                              int* __restrict__ csr_src) {
  int stride = gridDim.x * blockDim.x;
  for (int e = blockIdx.x * blockDim.x + threadIdx.x; e < NE; e += stride) {
    int pos = atomicAdd(&fill[ei[NE + e]], 1);
    csr_src[pos] = ei[e];
  }
}

// ---------------- weight transpose prep ----------------
// WT[j][k] = W[k][j]; scalar-load-friendly layout for k_gemm.

__global__ __launch_bounds__(256) void k_prep(const float* __restrict__ Wl1,
                                              const float* __restrict__ Wr1,
                                              const float* __restrict__ Wlin,
                                              const float* __restrict__ Wl2,
                                              const float* __restrict__ Wr2,
                                              float* __restrict__ WT1,
                                              float* __restrict__ WlinT,
                                              float* __restrict__ WT2) {
  int id0 = blockIdx.x * blockDim.x + threadIdx.x;
  int ns  = gridDim.x * blockDim.x;
  for (int i = id0; i < F * H; i += ns) { int k = i >> 6, j = i & 63; WT1[j * F + k] = Wl1[i]; }
  for (int i = id0; i < F * H; i += ns) { int k = i >> 6, j = i & 63; WT1[F * H + j * F + k] = Wr1[i]; }
  for (int i = id0; i < (F + H) * H; i += ns) { int k = i >> 6, j = i & 63; WlinT[j * (F + H) + k] = Wlin[i]; }
  for (int i = id0; i < H * C; i += ns) { int k = i / C, j = i % C; WT2[j * H + k] = Wl2[i]; }
  for (int i = id0; i < H * C; i += ns) { int k = i / C, j = i % C; WT2[H * C + j * H + k] = Wr2[i]; }
}

// ---------------- dense: lane = node, scalar-uniform weights ----------------
// Y[mat][node][jb*JT+j] = sum_k [X1|X2][node][k] * WT[mat][jb*JT+j][k] (+bias, relu)
// Weight reads are wave-uniform -> s_load (scalar pipe); X reads/stores are
// per-lane float4 on the lane's own row. Zero LDS, zero shfl.

template <int K1, int K2, int J, int JT, bool BIAS, bool RELU>
__global__ __launch_bounds__(256) void k_gemm(const float* __restrict__ X1,
                                              const float* __restrict__ X2,
                                              const float* __restrict__ WT,
                                              const float* __restrict__ bias,
                                              float* __restrict__ Y,
                                              int nmat, int wstride, long ystride) {
  constexpr int K  = K1 + K2;
  constexpr int NJ = J / JT;
  const int ntiles = (NN + 63) >> 6;
  int lane = threadIdx.x & 63;
  int widv = (blockIdx.x * blockDim.x + threadIdx.x) >> 6;
  int wid  = __builtin_amdgcn_readfirstlane(widv);  // force SGPR: weight addrs scalar
  int nw   = (gridDim.x * blockDim.x) >> 6;
  int nwork = ntiles * NJ * nmat;
  for (int w = wid; w < nwork; w += nw) {
    int tile = w % ntiles;
    int rest = w / ntiles;
    int jb   = rest % NJ;
    int mat  = rest / NJ;
    int node = (tile << 6) + lane;
    bool valid = node < NN;
    int nr = valid ? node : NN - 1;  // clamp: loads stay in-bounds, stores masked
    const float* wt = WT + (size_t)mat * wstride + (size_t)(jb * JT) * K;
    float acc[JT];
#pragma unroll
    for (int j = 0; j < JT; ++j) acc[j] = BIAS ? bias[jb * JT + j] : 0.f;

    const float4* xp1 = reinterpret_cast<const float4*>(X1 + (size_t)nr * K1);
#pragma unroll 1
    for (int kc = 0; kc < K1 / 32; ++kc) {
      float xr[32];
#pragma unroll
      for (int v = 0; v < 8; ++v) {
        float4 t = xp1[kc * 8 + v];
        xr[v * 4 + 0] = t.x; xr[v * 4 + 1] = t.y;
        xr[v * 4 + 2] = t.z; xr[v * 4 + 3] = t.w;
      }
#pragma unroll
      for (int j = 0; j < JT; ++j) {
        const float* wr = wt + j * K + kc * 32;
#pragma unroll
        for (int k = 0; k < 32; ++k) acc[j] += xr[k] * wr[k];
      }
    }
    if constexpr (K2 > 0) {
      const float4* xp2 = reinterpret_cast<const float4*>(X2 + (size_t)nr * K2);
#pragma unroll 1
      for (int kc = 0; kc < K2 / 32; ++kc) {
        float xr[32];
#pragma unroll
        for (int v = 0; v < 8; ++v) {
          float4 t = xp2[kc * 8 + v];
          xr[v * 4 + 0] = t.x; xr[v * 4 + 1] = t.y;
          xr[v * 4 + 2] = t.z; xr[v * 4 + 3] = t.w;
        }
#pragma unroll
        for (int j = 0; j < JT; ++j) {
          const float* wr = wt + j * K + K1 + kc * 32;
#pragma unroll
          for (int k = 0; k < 32; ++k) acc[j] += xr[k] * wr[k];
        }
      }
    }
    if (valid) {
      float* yp = Y + (size_t)mat * ystride + (size_t)node * J + jb * JT;
#pragma unroll
      for (int j = 0; j < JT; j += 4) {
        float4 t = {acc[j], acc[j + 1], acc[j + 2], acc[j + 3]};
        if (RELU) {
          t.x = fmaxf(t.x, 0.f); t.y = fmaxf(t.y, 0.f);
          t.z = fmaxf(t.z, 0.f); t.w = fmaxf(t.w, 0.f);
        }
        reinterpret_cast<float4*>(yp)[j >> 2] = t;
      }
    }
  }
}

// ---------------- Aggregate conv1 + bias + l2norm + relu -> hidden ----------

__global__ __launch_bounds__(256) void k_agg1(const float* __restrict__ p,
                                              const float* __restrict__ q,
                                              const float* __restrict__ bl,
                                              const int* __restrict__ deg,
                                              const int* __restrict__ start,
                                              const int* __restrict__ csr_src,
                                              float* __restrict__ hidden) {
  int lane = threadIdx.x & 63;
  int wid  = (blockIdx.x * blockDim.x + threadIdx.x) >> 6;
  int nw   = (gridDim.x * blockDim.x) >> 6;
  for (int node = wid; node < NN; node += nw) {
    int d = deg[node], st = start[node];
    float acc = 0.f;
    for (int b = 0; b < d; b += 64) {
      int rem = d - b;
      int cnt = rem < 64 ? rem : 64;
      int nid = (lane < cnt) ? csr_src[st + b + lane] : 0;
      for (int t = 0; t < cnt; ++t) {
        int s = __shfl(nid, t, 64);
        acc += p[s * H + lane];
      }
    }
    float mean = acc / fmaxf((float)d, 1.0f);
    float v = mean + bl[lane] + q[node * H + lane];
    float ss = v * v;
#pragma unroll
    for (int off = 32; off > 0; off >>= 1) ss += __shfl_xor(ss, off, 64);
    v = v / fmaxf(sqrtf(ss), 1e-12f);
    hidden[node * H + lane] = fmaxf(v, 0.f);
  }
}

// ---------------- Aggregate conv2 + bias + l2norm -> out --------------------

__global__ __launch_bounds__(256) void k_agg2(const float* __restrict__ p2,
                                              const float* __restrict__ q2,
                                              const float* __restrict__ bl,
                                              const int* __restrict__ deg,
                                              const int* __restrict__ start,
                                              const int* __restrict__ csr_src,
                                              float* __restrict__ out) {
  int lane = threadIdx.x & 63;
  int wid  = (blockIdx.x * blockDim.x + threadIdx.x) >> 6;
  int nw   = (gridDim.x * blockDim.x) >> 6;
  for (int node = wid; node < NN; node += nw) {
    int d = deg[node], st = start[node];
    float acc = 0.f;
    for (int b = 0; b < d; b += 64) {
      int rem = d - b;
      int cnt = rem < 64 ? rem : 64;
      int nid = (lane < cnt) ? csr_src[st + b + lane] : 0;
      for (int t = 0; t < cnt; ++t) {
        int s = __shfl(nid, t, 64);
        if (lane < C) acc += p2[s * C + lane];
      }
    }
    float mean = acc / fmaxf((float)d, 1.0f);
    float v = 0.f;
    if (lane < C) v = mean + bl[lane] + q2[node * C + lane];
    float ss = v * v;
#pragma unroll
    for (int off = 32; off > 0; off >>= 1) ss += __shfl_xor(ss, off, 64);
    v = v / fmaxf(sqrtf(ss), 1e-12f);
    if (lane < C) out[node * C + lane] = v;
  }
}

// ---------------- launch ----------------------------------------------------

static inline size_t align256(size_t x) { return (x + 255) & ~(size_t)255; }

extern "C" void kernel_launch(void* const* d_in, const int* in_sizes, int n_in,
                              void* d_out, int out_size, void* d_ws, size_t ws_size,
                              hipStream_t stream) {
  const float* x    = (const float*)d_in[0];
  const int*   ei   = (const int*)d_in[1];
  const float* Wl1  = (const float*)d_in[2];
  const float* bl1  = (const float*)d_in[3];
  const float* Wr1  = (const float*)d_in[4];
  const float* Wlin = (const float*)d_in[5];
  const float* blin = (const float*)d_in[6];
  const float* Wl2  = (const float*)d_in[7];
  const float* bl2  = (const float*)d_in[8];
  const float* Wr2  = (const float*)d_in[9];
  float* out = (float*)d_out;

  char* w = (char*)d_ws;
  size_t off = 0;
  int* deg     = (int*)(w + off); off += align256((size_t)NN * 4);
  int* start   = (int*)(w + off); off += align256((size_t)NN * 4);
  int* fill    = (int*)(w + off); off += align256((size_t)NN * 4);
  int* counter = (int*)(w + off); off += 256;
  int* csr_src = (int*)(w + off); off += align256((size_t)NE * 4);
  float* WT1   = (float*)(w + off); off += align256((size_t)2 * F * H * 4);
  float* WlinT = (float*)(w + off); off += align256((size_t)(F + H) * H * 4);
  float* WT2   = (float*)(w + off); off += align256((size_t)2 * H * C * 4);
  // big region: [0, 2*NN*H) = p,q for conv1; after agg1 dead ->
  //   h at [0, NN*H), p2q2 at [NN*H, NN*H + 2*NN*C)
  float* big   = (float*)(w + off); off += align256(((size_t)2 * NN * H + 2 * (size_t)NN * C) * 4);
  float* hidden= (float*)(w + off); off += align256((size_t)NN * H * 4);

  float* p1 = big;
  float* q1 = big + (size_t)NN * H;
  float* h  = big;
  float* p2 = big + (size_t)NN * H;

  hipMemsetAsync(deg, 0, (size_t)NN * 4, stream);
  hipMemsetAsync(counter, 0, 4, stream);

  const int T = 256;
  k_prep  <<<64,  T, 0, stream>>>(Wl1, Wr1, Wlin, Wl2, Wr2, WT1, WlinT, WT2);
  k_count <<<512, T, 0, stream>>>(ei, deg);
  k_ranges<<<128, T, 0, stream>>>(deg, start, fill, counter);
  k_fill  <<<512, T, 0, stream>>>(ei, fill, csr_src);

  // conv1 projections: p1 = x@Wl1, q1 = x@Wr1  (nmat=2, JT=32 -> 3128 waves)
  k_gemm<F, 0, H, 32, false, false><<<782, T, 0, stream>>>(
      x, nullptr, WT1, nullptr, p1, 2, F * H, (long)NN * H);
  // hidden = relu(l2norm(mean_agg(p1) + bl1 + q1))
  k_agg1<<<1024, T, 0, stream>>>(p1, q1, bl1, deg, start, csr_src, hidden);
  // h = relu([x, hidden] @ Wlin + blin)   (p1,q1 dead; h overwrites p1)
  k_gemm<F, H, H, 32, true, true><<<391, T, 0, stream>>>(
      x, hidden, WlinT, blin, h, 1, 0, 0);
  // conv2 projections: p2 = h@Wl2, q2 = h@Wr2
  k_gemm<H, 0, C, 40, false, false><<<391, T, 0, stream>>>(
      h, nullptr, WT2, nullptr, p2, 2, H * C, (long)NN * C);
  // out = l2norm(mean_agg(p2) + bl2 + q2)
  k_agg2<<<1024, T, 0, stream>>>(p2, p2 + (size_t)NN * C, bl2, deg, start, csr_src, out);
}

// Round 3
// 570.341 us; speedup vs baseline: 1.7728x; 1.1611x over previous
//
#include <hip/hip_runtime.h>

static constexpr int NN = 50000;   // nodes
static constexpr int NE = 800000;  // edges
static constexpr int F  = 128;     // input features
static constexpr int H  = 64;      // hidden
static constexpr int C  = 40;      // classes

// ---------------- CSR build ----------------

__global__ __launch_bounds__(256) void k_count(const int* __restrict__ ei,
                                               int* __restrict__ deg) {
  int stride = gridDim.x * blockDim.x;
  for (int e = blockIdx.x * blockDim.x + threadIdx.x; e < NE; e += stride)
    atomicAdd(&deg[ei[NE + e]], 1);  // dst = ei[1][e]
}

__global__ __launch_bounds__(256) void k_ranges(const int* __restrict__ deg,
                                                int* __restrict__ start,
                                                int* __restrict__ fill,
                                                int* __restrict__ counter) {
  int lane = threadIdx.x & 63;
  int wid  = (blockIdx.x * blockDim.x + threadIdx.x) >> 6;
  int nw   = (gridDim.x * blockDim.x) >> 6;
  int nchunks = (NN + 63) >> 6;
  for (int c = wid; c < nchunks; c += nw) {
    int i = (c << 6) + lane;
    int v = (i < NN) ? deg[i] : 0;
    int inc = v;
#pragma unroll
    for (int off = 1; off < 64; off <<= 1) {
      int t = __shfl_up(inc, off, 64);
      if (lane >= off) inc += t;
    }
    int total = __shfl(inc, 63, 64);
    int base = 0;
    if (lane == 63) base = atomicAdd(counter, total);
    base = __shfl(base, 63, 64);
    if (i < NN) {
      int s = base + inc - v;
      start[i] = s;
      fill[i]  = s;
    }
  }
}

__global__ __launch_bounds__(256) void k_fill(const int* __restrict__ ei,
                                              int* __restrict__ fill,
                                              int* __restrict__ csr_src) {
  int stride = gridDim.x * blockDim.x;
  for (int e = blockIdx.x * blockDim.x + threadIdx.x; e < NE; e += stride) {
    int pos = atomicAdd(&fill[ei[NE + e]], 1);
    csr_src[pos] = ei[e];
  }
}

// ---------------- transpose: src [NN][ncols] -> dst [ncols][NN] -------------

__global__ __launch_bounds__(256) void k_tr(const float* __restrict__ src,
                                            float* __restrict__ dst,
                                            int ncols) {
  __shared__ float t[64][65];
  int rtiles = (NN + 63) >> 6;
  int rt = blockIdx.x % rtiles;
  int ct = blockIdx.x / rtiles;
  int tx = threadIdx.x & 63;
  int ty = threadIdx.x >> 6;
  int rb = rt << 6, cb = ct << 6;
#pragma unroll
  for (int i = 0; i < 16; ++i) {
    int r = rb + ty + i * 4;
    if (r < NN) t[ty + i * 4][tx] = src[(size_t)r * ncols + cb + tx];
  }
  __syncthreads();
  int r2 = rb + tx;
  if (r2 < NN) {
#pragma unroll
    for (int i = 0; i < 16; ++i) {
      int c = ty + i * 4;
      dst[(size_t)(cb + c) * NN + r2] = t[tx][c];
    }
  }
}

// ---------------- dense GEMM: lane = 4 consecutive nodes, SGPR weights ------
// X1T/X2T are [K][NN] (transposed); W is ORIGINAL [K][J] row-major; per k:
// 1 coalesced float4 node-load + 1 s_load_dwordx16 of weights reused for
// 4 nodes x JT j's = 64 FMAs. Scalar traffic / MAC is 1/16 B.

template <int K1, int K2, int J, int JT, bool BIAS, bool RELU, bool TSTORE>
__global__ __launch_bounds__(256) void k_gemm(const float* __restrict__ X1T,
                                              const float* __restrict__ X2T,
                                              const float* __restrict__ W,
                                              const float* __restrict__ bias,
                                              float* __restrict__ Y,
                                              int nmat, int wstride, long ystride) {
  constexpr int NJ = J / JT;
  const int ntiles = (NN + 255) >> 8;
  int lane = threadIdx.x & 63;
  int widv = (blockIdx.x * blockDim.x + threadIdx.x) >> 6;
  int nw   = (gridDim.x * blockDim.x) >> 6;
  int nwork = ntiles * NJ * nmat;
  for (int w0 = widv; w0 < nwork; w0 += nw) {
    int w = __builtin_amdgcn_readfirstlane(w0);  // keep weight addressing scalar
    int tile = w % ntiles;
    int rest = w / ntiles;
    int jb   = rest % NJ;
    int mat  = rest / NJ;
    int n0 = (tile << 8) + 4 * lane;
    int nc = (n0 <= NN - 4) ? n0 : (NN - 4);  // clamped load base (stores masked)
    const float* wm = W + (size_t)mat * wstride + jb * JT;
    float acc[4][JT];
#pragma unroll
    for (int j = 0; j < JT; ++j) {
      float b = BIAS ? bias[jb * JT + j] : 0.f;
      acc[0][j] = b; acc[1][j] = b; acc[2][j] = b; acc[3][j] = b;
    }
    {
      const float* xcol = X1T + nc;
#pragma unroll 4
      for (int k = 0; k < K1; ++k) {
        float4 xv = *reinterpret_cast<const float4*>(xcol + (size_t)k * NN);
        const float* wr = wm + k * J;
#pragma unroll
        for (int j = 0; j < JT; ++j) {
          float wj = wr[j];
          acc[0][j] += xv.x * wj;
          acc[1][j] += xv.y * wj;
          acc[2][j] += xv.z * wj;
          acc[3][j] += xv.w * wj;
        }
      }
    }
    if constexpr (K2 > 0) {
      const float* xcol = X2T + nc;
#pragma unroll 4
      for (int k = 0; k < K2; ++k) {
        float4 xv = *reinterpret_cast<const float4*>(xcol + (size_t)k * NN);
        const float* wr = wm + (K1 + k) * J;
#pragma unroll
        for (int j = 0; j < JT; ++j) {
          float wj = wr[j];
          acc[0][j] += xv.x * wj;
          acc[1][j] += xv.y * wj;
          acc[2][j] += xv.z * wj;
          acc[3][j] += xv.w * wj;
        }
      }
    }
    if (n0 < NN) {  // NN%4==0 -> all 4 nodes valid together
      if constexpr (TSTORE) {
#pragma unroll
        for (int j = 0; j < JT; ++j) {
          float4 t = {acc[0][j], acc[1][j], acc[2][j], acc[3][j]};
          if (RELU) {
            t.x = fmaxf(t.x, 0.f); t.y = fmaxf(t.y, 0.f);
            t.z = fmaxf(t.z, 0.f); t.w = fmaxf(t.w, 0.f);
          }
          *reinterpret_cast<float4*>(Y + (size_t)(jb * JT + j) * NN + n0) = t;
        }
      } else {
#pragma unroll
        for (int i = 0; i < 4; ++i) {
          float* yp = Y + (size_t)mat * ystride + (size_t)(n0 + i) * J + jb * JT;
#pragma unroll
          for (int j = 0; j < JT; j += 4) {
            float4 t = {acc[i][j], acc[i][j + 1], acc[i][j + 2], acc[i][j + 3]};
            if (RELU) {
              t.x = fmaxf(t.x, 0.f); t.y = fmaxf(t.y, 0.f);
              t.z = fmaxf(t.z, 0.f); t.w = fmaxf(t.w, 0.f);
            }
            *reinterpret_cast<float4*>(yp + j) = t;
          }
        }
      }
    }
  }
}

// ---------------- Aggregate conv1 + bias + l2norm + relu -> hidden ----------

__global__ __launch_bounds__(256) void k_agg1(const float* __restrict__ p,
                                              const float* __restrict__ q,
                                              const float* __restrict__ bl,
                                              const int* __restrict__ deg,
                                              const int* __restrict__ start,
                                              const int* __restrict__ csr_src,
                                              float* __restrict__ hidden) {
  int lane = threadIdx.x & 63;
  int wid  = (blockIdx.x * blockDim.x + threadIdx.x) >> 6;
  int nw   = (gridDim.x * blockDim.x) >> 6;
  for (int node = wid; node < NN; node += nw) {
    int d = deg[node], st = start[node];
    float acc = 0.f;
    for (int b = 0; b < d; b += 64) {
      int rem = d - b;
      int cnt = rem < 64 ? rem : 64;
      int nid = (lane < cnt) ? csr_src[st + b + lane] : 0;
      for (int t = 0; t < cnt; ++t) {
        int s = __shfl(nid, t, 64);
        acc += p[s * H + lane];
      }
    }
    float mean = acc / fmaxf((float)d, 1.0f);
    float v = mean + bl[lane] + q[node * H + lane];
    float ss = v * v;
#pragma unroll
    for (int off = 32; off > 0; off >>= 1) ss += __shfl_xor(ss, off, 64);
    v = v / fmaxf(sqrtf(ss), 1e-12f);
    hidden[node * H + lane] = fmaxf(v, 0.f);
  }
}

// ---------------- Aggregate conv2 + bias + l2norm -> out --------------------

__global__ __launch_bounds__(256) void k_agg2(const float* __restrict__ p2,
                                              const float* __restrict__ q2,
                                              const float* __restrict__ bl,
                                              const int* __restrict__ deg,
                                              const int* __restrict__ start,
                                              const int* __restrict__ csr_src,
                                              float* __restrict__ out) {
  int lane = threadIdx.x & 63;
  int wid  = (blockIdx.x * blockDim.x + threadIdx.x) >> 6;
  int nw   = (gridDim.x * blockDim.x) >> 6;
  for (int node = wid; node < NN; node += nw) {
    int d = deg[node], st = start[node];
    float acc = 0.f;
    for (int b = 0; b < d; b += 64) {
      int rem = d - b;
      int cnt = rem < 64 ? rem : 64;
      int nid = (lane < cnt) ? csr_src[st + b + lane] : 0;
      for (int t = 0; t < cnt; ++t) {
        int s = __shfl(nid, t, 64);
        if (lane < C) acc += p2[s * C + lane];
      }
    }
    float mean = acc / fmaxf((float)d, 1.0f);
    float v = 0.f;
    if (lane < C) v = mean + bl[lane] + q2[node * C + lane];
    float ss = v * v;
#pragma unroll
    for (int off = 32; off > 0; off >>= 1) ss += __shfl_xor(ss, off, 64);
    v = v / fmaxf(sqrtf(ss), 1e-12f);
    if (lane < C) out[node * C + lane] = v;
  }
}

// ---------------- launch ----------------------------------------------------

static inline size_t align256(size_t x) { return (x + 255) & ~(size_t)255; }

extern "C" void kernel_launch(void* const* d_in, const int* in_sizes, int n_in,
                              void* d_out, int out_size, void* d_ws, size_t ws_size,
                              hipStream_t stream) {
  const float* x    = (const float*)d_in[0];
  const int*   ei   = (const int*)d_in[1];
  const float* Wl1  = (const float*)d_in[2];
  const float* bl1  = (const float*)d_in[3];
  const float* Wr1  = (const float*)d_in[4];
  const float* Wlin = (const float*)d_in[5];
  const float* blin = (const float*)d_in[6];
  const float* Wl2  = (const float*)d_in[7];
  const float* bl2  = (const float*)d_in[8];
  const float* Wr2  = (const float*)d_in[9];
  float* out = (float*)d_out;

  char* w = (char*)d_ws;
  size_t off = 0;
  int* deg     = (int*)(w + off); off += align256((size_t)NN * 4);
  int* start   = (int*)(w + off); off += align256((size_t)NN * 4);
  int* fill    = (int*)(w + off); off += align256((size_t)NN * 4);
  int* counter = (int*)(w + off); off += 256;
  int* csr_src = (int*)(w + off); off += align256((size_t)NE * 4);
  float* xt    = (float*)(w + off); off += align256((size_t)F * NN * 4);   // 25.6 MB
  float* bufP  = (float*)(w + off); off += align256((size_t)2 * NN * H * 4); // 25.6 MB
  float* hidden= (float*)(w + off); off += align256((size_t)NN * H * 4);   // 12.8 MB

  // liveness overlays:
  float* p1      = bufP;                       // live: gemm1 -> agg1
  float* q1      = bufP + (size_t)NN * H;      // live: gemm1 -> agg1
  float* hiddenT = bufP;                       // live: tr(hidden) -> lin1 (p1 dead)
  float* hT      = bufP + (size_t)NN * H;      // live: lin1 -> gemm2 (q1 dead)
  float* p2      = xt;                         // live: gemm2 -> agg2 (xt dead)
  float* q2      = xt + (size_t)NN * C;

  hipMemsetAsync(deg, 0, (size_t)NN * 4, stream);
  hipMemsetAsync(counter, 0, 4, stream);

  const int T = 256;
  k_count <<<512, T, 0, stream>>>(ei, deg);
  k_ranges<<<128, T, 0, stream>>>(deg, start, fill, counter);
  k_fill  <<<512, T, 0, stream>>>(ei, fill, csr_src);

  // xt = x^T  [F][NN]
  k_tr<<<782 * (F / 64), T, 0, stream>>>(x, xt, F);

  // p1 = x@Wl1, q1 = x@Wr1   (ntiles=196, NJ=4, nmat=2 -> 1568 wave-items)
  k_gemm<F, 0, H, 16, false, false, false><<<392, T, 0, stream>>>(
      xt, nullptr, Wl1, nullptr, p1, 2, F * H, (long)NN * H);
  // Wr1 is a separate input array; pass via mat=1 trick won't work (non-contiguous).
  // -> run second mat as its own launch reusing the same template:
  k_gemm<F, 0, H, 16, false, false, false><<<196, T, 0, stream>>>(
      xt, nullptr, Wr1, nullptr, q1, 1, 0, 0);

  // hidden = relu(l2norm(mean_agg(p1) + bl1 + q1))
  k_agg1<<<1024, T, 0, stream>>>(p1, q1, bl1, deg, start, csr_src, hidden);

  // hiddenT = hidden^T [H][NN]  (p1 region dead)
  k_tr<<<782 * (H / 64), T, 0, stream>>>(hidden, hiddenT, H);

  // hT = relu([x, hidden] @ Wlin + blin)^T  [H][NN]
  k_gemm<F, H, H, 16, true, true, true><<<196, T, 0, stream>>>(
      xt, hiddenT, Wlin, blin, hT, 1, 0, 0);

  // p2 = h@Wl2, q2 = h@Wr2  (xt dead -> reuse region)
  k_gemm<H, 0, C, 20, false, false, false><<<98, T, 0, stream>>>(
      hT, nullptr, Wl2, nullptr, p2, 1, 0, 0);
  k_gemm<H, 0, C, 20, false, false, false><<<98, T, 0, stream>>>(
      hT, nullptr, Wr2, nullptr, q2, 1, 0, 0);

  // out = l2norm(mean_agg(p2) + bl2 + q2)
  k_agg2<<<1024, T, 0, stream>>>(p2, q2, bl2, deg, start, csr_src, out);
}

// Round 4
// 430.115 us; speedup vs baseline: 2.3508x; 1.3260x over previous
//
#include <hip/hip_runtime.h>

static constexpr int NN = 50000;   // nodes
static constexpr int NE = 800000;  // edges
static constexpr int F  = 128;     // input features
static constexpr int H  = 64;      // hidden
static constexpr int C  = 40;      // classes

// ---------------- CSR build ----------------

__global__ __launch_bounds__(256) void k_count(const int* __restrict__ ei,
                                               int* __restrict__ deg) {
  int stride = gridDim.x * blockDim.x;
  for (int e = blockIdx.x * blockDim.x + threadIdx.x; e < NE; e += stride)
    atomicAdd(&deg[ei[NE + e]], 1);  // dst = ei[1][e]
}

__global__ __launch_bounds__(256) void k_ranges(const int* __restrict__ deg,
                                                int* __restrict__ start,
                                                int* __restrict__ fill,
                                                int* __restrict__ counter) {
  int lane = threadIdx.x & 63;
  int wid  = (blockIdx.x * blockDim.x + threadIdx.x) >> 6;
  int nw   = (gridDim.x * blockDim.x) >> 6;
  int nchunks = (NN + 63) >> 6;
  for (int c = wid; c < nchunks; c += nw) {
    int i = (c << 6) + lane;
    int v = (i < NN) ? deg[i] : 0;
    int inc = v;
#pragma unroll
    for (int off = 1; off < 64; off <<= 1) {
      int t = __shfl_up(inc, off, 64);
      if (lane >= off) inc += t;
    }
    int total = __shfl(inc, 63, 64);
    int base = 0;
    if (lane == 63) base = atomicAdd(counter, total);
    base = __shfl(base, 63, 64);
    if (i < NN) {
      int s = base + inc - v;
      start[i] = s;
      fill[i]  = s;
    }
  }
}

__global__ __launch_bounds__(256) void k_fill(const int* __restrict__ ei,
                                              int* __restrict__ fill,
                                              int* __restrict__ csr_src) {
  int stride = gridDim.x * blockDim.x;
  for (int e = blockIdx.x * blockDim.x + threadIdx.x; e < NE; e += stride) {
    int pos = atomicAdd(&fill[ei[NE + e]], 1);
    csr_src[pos] = ei[e];
  }
}

// ---------------- transpose: src [NN][ncols] -> dst [ncols][NN] -------------

__global__ __launch_bounds__(256) void k_tr(const float* __restrict__ src,
                                            float* __restrict__ dst,
                                            int ncols) {
  __shared__ float t[64][65];
  int rtiles = (NN + 63) >> 6;
  int rt = blockIdx.x % rtiles;
  int ct = blockIdx.x / rtiles;
  int tx = threadIdx.x & 63;
  int ty = threadIdx.x >> 6;
  int rb = rt << 6, cb = ct << 6;
#pragma unroll
  for (int i = 0; i < 16; ++i) {
    int r = rb + ty + i * 4;
    if (r < NN) t[ty + i * 4][tx] = src[(size_t)r * ncols + cb + tx];
  }
  __syncthreads();
  int r2 = rb + tx;
  if (r2 < NN) {
#pragma unroll
    for (int i = 0; i < 16; ++i) {
      int c = ty + i * 4;
      dst[(size_t)(cb + c) * NN + r2] = t[tx][c];
    }
  }
}

// ---------------- dense GEMM: lane = 4 consecutive nodes, SGPR weights ------

template <int K1, int K2, int J, int JT, bool BIAS, bool RELU, bool TSTORE>
__global__ __launch_bounds__(256) void k_gemm(const float* __restrict__ X1T,
                                              const float* __restrict__ X2T,
                                              const float* __restrict__ W,
                                              const float* __restrict__ bias,
                                              float* __restrict__ Y) {
  constexpr int NJ = J / JT;
  const int ntiles = (NN + 255) >> 8;
  int lane = threadIdx.x & 63;
  int widv = (blockIdx.x * blockDim.x + threadIdx.x) >> 6;
  int nw   = (gridDim.x * blockDim.x) >> 6;
  int nwork = ntiles * NJ;
  for (int w0 = widv; w0 < nwork; w0 += nw) {
    int w = __builtin_amdgcn_readfirstlane(w0);  // keep weight addressing scalar
    int tile = w % ntiles;
    int jb   = w / ntiles;
    int n0 = (tile << 8) + 4 * lane;
    int nc = (n0 <= NN - 4) ? n0 : (NN - 4);  // clamped load base (stores masked)
    const float* wm = W + jb * JT;
    float acc[4][JT];
#pragma unroll
    for (int j = 0; j < JT; ++j) {
      float b = BIAS ? bias[jb * JT + j] : 0.f;
      acc[0][j] = b; acc[1][j] = b; acc[2][j] = b; acc[3][j] = b;
    }
    {
      const float* xcol = X1T + nc;
#pragma unroll 4
      for (int k = 0; k < K1; ++k) {
        float4 xv = *reinterpret_cast<const float4*>(xcol + (size_t)k * NN);
        const float* wr = wm + k * J;
#pragma unroll
        for (int j = 0; j < JT; ++j) {
          float wj = wr[j];
          acc[0][j] += xv.x * wj;
          acc[1][j] += xv.y * wj;
          acc[2][j] += xv.z * wj;
          acc[3][j] += xv.w * wj;
        }
      }
    }
    if constexpr (K2 > 0) {
      const float* xcol = X2T + nc;
#pragma unroll 4
      for (int k = 0; k < K2; ++k) {
        float4 xv = *reinterpret_cast<const float4*>(xcol + (size_t)k * NN);
        const float* wr = wm + (K1 + k) * J;
#pragma unroll
        for (int j = 0; j < JT; ++j) {
          float wj = wr[j];
          acc[0][j] += xv.x * wj;
          acc[1][j] += xv.y * wj;
          acc[2][j] += xv.z * wj;
          acc[3][j] += xv.w * wj;
        }
      }
    }
    if (n0 < NN) {  // NN%4==0 -> all 4 nodes valid together
      if constexpr (TSTORE) {
#pragma unroll
        for (int j = 0; j < JT; ++j) {
          float4 t = {acc[0][j], acc[1][j], acc[2][j], acc[3][j]};
          if (RELU) {
            t.x = fmaxf(t.x, 0.f); t.y = fmaxf(t.y, 0.f);
            t.z = fmaxf(t.z, 0.f); t.w = fmaxf(t.w, 0.f);
          }
          *reinterpret_cast<float4*>(Y + (size_t)(jb * JT + j) * NN + n0) = t;
        }
      } else {
#pragma unroll
        for (int i = 0; i < 4; ++i) {
          float* yp = Y + (size_t)(n0 + i) * J + jb * JT;
#pragma unroll
          for (int j = 0; j < JT; j += 4) {
            float4 t = {acc[i][j], acc[i][j + 1], acc[i][j + 2], acc[i][j + 3]};
            if (RELU) {
              t.x = fmaxf(t.x, 0.f); t.y = fmaxf(t.y, 0.f);
              t.z = fmaxf(t.z, 0.f); t.w = fmaxf(t.w, 0.f);
            }
            *reinterpret_cast<float4*>(yp + j) = t;
          }
        }
      }
    }
  }
}

// ---------------- aggregation: scalar CSR fetch + 8-deep gather MLP ---------
// Neighbor ids come from wave-uniform addresses -> s_load (no shfl, no DS).
// 8 independent row-gathers in flight per wave breaks the 1-load-per-latency
// serialization (was ~1190 cyc/edge).

template <int JC, bool RELU>
__global__ __launch_bounds__(256) void k_agg(const float* __restrict__ p,
                                             const float* __restrict__ q,
                                             const float* __restrict__ bl,
                                             const int* __restrict__ deg,
                                             const int* __restrict__ start,
                                             const int* __restrict__ csr_src,
                                             float* __restrict__ outp) {
  int lane = threadIdx.x & 63;
  int wid  = (blockIdx.x * blockDim.x + threadIdx.x) >> 6;
  int nw   = (gridDim.x * blockDim.x) >> 6;
  bool jl = lane < JC;
  int lidx = jl ? lane : 0;  // clamped feature index for idle lanes
  for (int node = wid; node < NN; node += nw) {
    int d  = __builtin_amdgcn_readfirstlane(deg[node]);
    int st = __builtin_amdgcn_readfirstlane(start[node]);
    float a0 = 0.f, a1 = 0.f, a2 = 0.f, a3 = 0.f;
    float a4 = 0.f, a5 = 0.f, a6 = 0.f, a7 = 0.f;
    int t = 0;
    for (; t + 8 <= d; t += 8) {
      int s0 = __builtin_amdgcn_readfirstlane(csr_src[st + t + 0]);
      int s1 = __builtin_amdgcn_readfirstlane(csr_src[st + t + 1]);
      int s2 = __builtin_amdgcn_readfirstlane(csr_src[st + t + 2]);
      int s3 = __builtin_amdgcn_readfirstlane(csr_src[st + t + 3]);
      int s4 = __builtin_amdgcn_readfirstlane(csr_src[st + t + 4]);
      int s5 = __builtin_amdgcn_readfirstlane(csr_src[st + t + 5]);
      int s6 = __builtin_amdgcn_readfirstlane(csr_src[st + t + 6]);
      int s7 = __builtin_amdgcn_readfirstlane(csr_src[st + t + 7]);
      a0 += p[(size_t)s0 * JC + lidx];
      a1 += p[(size_t)s1 * JC + lidx];
      a2 += p[(size_t)s2 * JC + lidx];
      a3 += p[(size_t)s3 * JC + lidx];
      a4 += p[(size_t)s4 * JC + lidx];
      a5 += p[(size_t)s5 * JC + lidx];
      a6 += p[(size_t)s6 * JC + lidx];
      a7 += p[(size_t)s7 * JC + lidx];
    }
    if (t + 4 <= d) {
      int s0 = __builtin_amdgcn_readfirstlane(csr_src[st + t + 0]);
      int s1 = __builtin_amdgcn_readfirstlane(csr_src[st + t + 1]);
      int s2 = __builtin_amdgcn_readfirstlane(csr_src[st + t + 2]);
      int s3 = __builtin_amdgcn_readfirstlane(csr_src[st + t + 3]);
      a0 += p[(size_t)s0 * JC + lidx];
      a1 += p[(size_t)s1 * JC + lidx];
      a2 += p[(size_t)s2 * JC + lidx];
      a3 += p[(size_t)s3 * JC + lidx];
      t += 4;
    }
    for (; t < d; ++t) {
      int s = __builtin_amdgcn_readfirstlane(csr_src[st + t]);
      a0 += p[(size_t)s * JC + lidx];
    }
    float acc = ((a0 + a1) + (a2 + a3)) + ((a4 + a5) + (a6 + a7));
    float mean = acc / fmaxf((float)d, 1.0f);
    float v = 0.f;
    if (jl) v = mean + bl[lidx] + q[(size_t)node * JC + lidx];
    float ss = v * v;
#pragma unroll
    for (int off = 32; off > 0; off >>= 1) ss += __shfl_xor(ss, off, 64);
    v = v / fmaxf(sqrtf(ss), 1e-12f);
    if (RELU) v = fmaxf(v, 0.f);
    if (jl) outp[(size_t)node * JC + lidx] = v;
  }
}

// ---------------- launch ----------------------------------------------------

static inline size_t align256(size_t x) { return (x + 255) & ~(size_t)255; }

extern "C" void kernel_launch(void* const* d_in, const int* in_sizes, int n_in,
                              void* d_out, int out_size, void* d_ws, size_t ws_size,
                              hipStream_t stream) {
  const float* x    = (const float*)d_in[0];
  const int*   ei   = (const int*)d_in[1];
  const float* Wl1  = (const float*)d_in[2];
  const float* bl1  = (const float*)d_in[3];
  const float* Wr1  = (const float*)d_in[4];
  const float* Wlin = (const float*)d_in[5];
  const float* blin = (const float*)d_in[6];
  const float* Wl2  = (const float*)d_in[7];
  const float* bl2  = (const float*)d_in[8];
  const float* Wr2  = (const float*)d_in[9];
  float* out = (float*)d_out;

  char* w = (char*)d_ws;
  size_t off = 0;
  int* deg     = (int*)(w + off); off += align256((size_t)NN * 4);
  int* start   = (int*)(w + off); off += align256((size_t)NN * 4);
  int* fill    = (int*)(w + off); off += align256((size_t)NN * 4);
  int* counter = (int*)(w + off); off += 256;
  int* csr_src = (int*)(w + off); off += align256((size_t)NE * 4);
  float* xt    = (float*)(w + off); off += align256((size_t)F * NN * 4);     // 25.6 MB
  float* bufP  = (float*)(w + off); off += align256((size_t)2 * NN * H * 4); // 25.6 MB
  float* hidden= (float*)(w + off); off += align256((size_t)NN * H * 4);     // 12.8 MB

  // liveness overlays:
  float* p1      = bufP;                       // gemm1 -> agg1
  float* q1      = bufP + (size_t)NN * H;      // gemm1 -> agg1
  float* hiddenT = bufP;                       // tr(hidden) -> lin1 (p1 dead)
  float* hT      = bufP + (size_t)NN * H;      // lin1 -> gemm2 (q1 dead)
  float* p2      = xt;                         // gemm2 -> agg2 (xt dead)
  float* q2      = xt + (size_t)NN * C;

  hipMemsetAsync(deg, 0, (size_t)NN * 4, stream);
  hipMemsetAsync(counter, 0, 4, stream);

  const int T = 256;
  k_count <<<1024, T, 0, stream>>>(ei, deg);
  k_ranges<<<128,  T, 0, stream>>>(deg, start, fill, counter);
  k_fill  <<<1024, T, 0, stream>>>(ei, fill, csr_src);

  // xt = x^T  [F][NN]
  k_tr<<<782 * (F / 64), T, 0, stream>>>(x, xt, F);

  // p1 = x@Wl1, q1 = x@Wr1
  k_gemm<F, 0, H, 16, false, false, false><<<196, T, 0, stream>>>(
      xt, nullptr, Wl1, nullptr, p1);
  k_gemm<F, 0, H, 16, false, false, false><<<196, T, 0, stream>>>(
      xt, nullptr, Wr1, nullptr, q1);

  // hidden = relu(l2norm(mean_agg(p1) + bl1 + q1))
  k_agg<H, true><<<2048, T, 0, stream>>>(p1, q1, bl1, deg, start, csr_src, hidden);

  // hiddenT = hidden^T [H][NN]  (p1 region dead)
  k_tr<<<782 * (H / 64), T, 0, stream>>>(hidden, hiddenT, H);

  // hT = relu([x, hidden] @ Wlin + blin)^T  [H][NN]
  k_gemm<F, H, H, 16, true, true, true><<<196, T, 0, stream>>>(
      xt, hiddenT, Wlin, blin, hT);

  // p2 = h@Wl2, q2 = h@Wr2  (xt dead -> reuse region)
  k_gemm<H, 0, C, 20, false, false, false><<<98, T, 0, stream>>>(
      hT, nullptr, Wl2, nullptr, p2);
  k_gemm<H, 0, C, 20, false, false, false><<<98, T, 0, stream>>>(
      hT, nullptr, Wr2, nullptr, q2);

  // out = l2norm(mean_agg(p2) + bl2 + q2)
  k_agg<C, false><<<2048, T, 0, stream>>>(p2, q2, bl2, deg, start, csr_src, out);
}

// Round 5
// 328.270 us; speedup vs baseline: 3.0801x; 1.3102x over previous
//
#include <hip/hip_runtime.h>

static constexpr int NN = 50000;   // nodes
static constexpr int NE = 800000;  // edges
static constexpr int F  = 128;     // input features
static constexpr int H  = 64;      // hidden
static constexpr int C  = 40;      // classes

static constexpr int NB_BK = 8;          // node buckets (XCD-aligned)
static constexpr int NCH   = 32;         // edge chunks
static constexpr int ECH   = NE / NCH;   // 25000 edges per chunk
static constexpr int NBK   = NN / NB_BK; // 6250 nodes per bucket

// ---------------- CSR build: XCD-aligned counting sort ----------------------
// bucket i = blockIdx&7 (round-robin block->XCD => one bucket per XCD),
// chunk j = blockIdx>>3. All slot assignment via LDS atomics; a node's CSR
// lines are written only from its bucket's XCD -> no L2 line ping-pong.

__global__ __launch_bounds__(256) void k_hist(const int* __restrict__ ei,
                                              int* __restrict__ hist) {
  __shared__ int cnt[NBK];
  int i = blockIdx.x & 7;
  int j = blockIdx.x >> 3;
  for (int t = threadIdx.x; t < NBK; t += 256) cnt[t] = 0;
  __syncthreads();
  int lo = i * NBK;
  const int* dst = ei + NE + j * ECH;
  for (int base = threadIdx.x * 4; base < ECH; base += 256 * 4) {
    int4 d4 = *reinterpret_cast<const int4*>(dst + base);
    if ((unsigned)(d4.x - lo) < (unsigned)NBK) atomicAdd(&cnt[d4.x - lo], 1);
    if ((unsigned)(d4.y - lo) < (unsigned)NBK) atomicAdd(&cnt[d4.y - lo], 1);
    if ((unsigned)(d4.z - lo) < (unsigned)NBK) atomicAdd(&cnt[d4.z - lo], 1);
    if ((unsigned)(d4.w - lo) < (unsigned)NBK) atomicAdd(&cnt[d4.w - lo], 1);
  }
  __syncthreads();
  int* hrow = hist + (size_t)j * NN + lo;
  for (int t = threadIdx.x; t < NBK; t += 256) hrow[t] = cnt[t];
}

// Per node: exclusive scan over chunk counts (-> per-chunk offsets, deg),
// then wave-scan + one global atomic for start[] (disjoint ranges, order
// arbitrary).
__global__ __launch_bounds__(256) void k_scan(int* __restrict__ hist,
                                              int* __restrict__ deg,
                                              int* __restrict__ start,
                                              int* __restrict__ counter) {
  int lane = threadIdx.x & 63;
  int wid  = (blockIdx.x * blockDim.x + threadIdx.x) >> 6;
  int nw   = (gridDim.x * blockDim.x) >> 6;
  int nchunks = (NN + 63) >> 6;
  for (int c = wid; c < nchunks; c += nw) {
    int n = (c << 6) + lane;
    int d = 0;
    if (n < NN) {
      int run = 0;
#pragma unroll
      for (int j = 0; j < NCH; ++j) {
        int v = hist[(size_t)j * NN + n];
        hist[(size_t)j * NN + n] = run;
        run += v;
      }
      d = run;
    }
    int inc = d;
#pragma unroll
    for (int off = 1; off < 64; off <<= 1) {
      int t = __shfl_up(inc, off, 64);
      if (lane >= off) inc += t;
    }
    int total = __shfl(inc, 63, 64);
    int base = 0;
    if (lane == 63) base = atomicAdd(counter, total);
    base = __shfl(base, 63, 64);
    if (n < NN) {
      deg[n]   = d;
      start[n] = base + inc - d;
    }
  }
}

__global__ __launch_bounds__(256) void k_fill2(const int* __restrict__ ei,
                                               const int* __restrict__ hist,
                                               const int* __restrict__ start,
                                               int* __restrict__ csr_src) {
  __shared__ int fill[NBK];
  int i = blockIdx.x & 7;
  int j = blockIdx.x >> 3;
  int lo = i * NBK;
  const int* hrow = hist + (size_t)j * NN + lo;
  for (int t = threadIdx.x; t < NBK; t += 256) fill[t] = start[lo + t] + hrow[t];
  __syncthreads();
  const int* srcp = ei + j * ECH;
  const int* dstp = ei + NE + j * ECH;
  for (int base = threadIdx.x * 4; base < ECH; base += 256 * 4) {
    int4 s4 = *reinterpret_cast<const int4*>(srcp + base);
    int4 d4 = *reinterpret_cast<const int4*>(dstp + base);
    if ((unsigned)(d4.x - lo) < (unsigned)NBK) { int p = atomicAdd(&fill[d4.x - lo], 1); csr_src[p] = s4.x; }
    if ((unsigned)(d4.y - lo) < (unsigned)NBK) { int p = atomicAdd(&fill[d4.y - lo], 1); csr_src[p] = s4.y; }
    if ((unsigned)(d4.z - lo) < (unsigned)NBK) { int p = atomicAdd(&fill[d4.z - lo], 1); csr_src[p] = s4.z; }
    if ((unsigned)(d4.w - lo) < (unsigned)NBK) { int p = atomicAdd(&fill[d4.w - lo], 1); csr_src[p] = s4.w; }
  }
}

// ---------------- transpose: src [NN][ncols] -> dst [ncols][NN] -------------

__global__ __launch_bounds__(256) void k_tr(const float* __restrict__ src,
                                            float* __restrict__ dst,
                                            int ncols) {
  __shared__ float t[64][65];
  int rtiles = (NN + 63) >> 6;
  int rt = blockIdx.x % rtiles;
  int ct = blockIdx.x / rtiles;
  int tx = threadIdx.x & 63;
  int ty = threadIdx.x >> 6;
  int rb = rt << 6, cb = ct << 6;
#pragma unroll
  for (int i = 0; i < 16; ++i) {
    int r = rb + ty + i * 4;
    if (r < NN) t[ty + i * 4][tx] = src[(size_t)r * ncols + cb + tx];
  }
  __syncthreads();
  int r2 = rb + tx;
  if (r2 < NN) {
#pragma unroll
    for (int i = 0; i < 16; ++i) {
      int c = ty + i * 4;
      dst[(size_t)(cb + c) * NN + r2] = t[tx][c];
    }
  }
}

// ---------------- dense GEMM: lane = 4 consecutive nodes, SGPR weights ------
// NMAT=2 runs two weight matrices / outputs in one launch (separate arrays).

template <int K1, int K2, int J, int JT, int NMAT, bool BIAS, bool RELU, bool TSTORE>
__global__ __launch_bounds__(256) void k_gemm(const float* __restrict__ X1T,
                                              const float* __restrict__ X2T,
                                              const float* __restrict__ W0,
                                              const float* __restrict__ W1,
                                              const float* __restrict__ bias,
                                              float* __restrict__ Y0,
                                              float* __restrict__ Y1) {
  constexpr int NJ = J / JT;
  const int ntiles = (NN + 255) >> 8;
  int lane = threadIdx.x & 63;
  int widv = (blockIdx.x * blockDim.x + threadIdx.x) >> 6;
  int nw   = (gridDim.x * blockDim.x) >> 6;
  int nwork = ntiles * NJ * NMAT;
  for (int w0 = widv; w0 < nwork; w0 += nw) {
    int w = __builtin_amdgcn_readfirstlane(w0);  // keep weight addressing scalar
    int tile = w % ntiles;
    int rest = w / ntiles;
    int jb   = rest % NJ;
    int mat  = rest / NJ;
    const float* W = (NMAT == 2 && mat == 1) ? W1 : W0;
    float*       Y = (NMAT == 2 && mat == 1) ? Y1 : Y0;
    int n0 = (tile << 8) + 4 * lane;
    int nc = (n0 <= NN - 4) ? n0 : (NN - 4);  // clamped load base (stores masked)
    const float* wm = W + jb * JT;
    float acc[4][JT];
#pragma unroll
    for (int j = 0; j < JT; ++j) {
      float b = BIAS ? bias[jb * JT + j] : 0.f;
      acc[0][j] = b; acc[1][j] = b; acc[2][j] = b; acc[3][j] = b;
    }
    {
      const float* xcol = X1T + nc;
#pragma unroll 4
      for (int k = 0; k < K1; ++k) {
        float4 xv = *reinterpret_cast<const float4*>(xcol + (size_t)k * NN);
        const float* wr = wm + k * J;
#pragma unroll
        for (int j = 0; j < JT; ++j) {
          float wj = wr[j];
          acc[0][j] += xv.x * wj;
          acc[1][j] += xv.y * wj;
          acc[2][j] += xv.z * wj;
          acc[3][j] += xv.w * wj;
        }
      }
    }
    if constexpr (K2 > 0) {
      const float* xcol = X2T + nc;
#pragma unroll 4
      for (int k = 0; k < K2; ++k) {
        float4 xv = *reinterpret_cast<const float4*>(xcol + (size_t)k * NN);
        const float* wr = wm + (K1 + k) * J;
#pragma unroll
        for (int j = 0; j < JT; ++j) {
          float wj = wr[j];
          acc[0][j] += xv.x * wj;
          acc[1][j] += xv.y * wj;
          acc[2][j] += xv.z * wj;
          acc[3][j] += xv.w * wj;
        }
      }
    }
    if (n0 < NN) {  // NN%4==0 -> all 4 nodes valid together
      if constexpr (TSTORE) {
#pragma unroll
        for (int j = 0; j < JT; ++j) {
          float4 t = {acc[0][j], acc[1][j], acc[2][j], acc[3][j]};
          if (RELU) {
            t.x = fmaxf(t.x, 0.f); t.y = fmaxf(t.y, 0.f);
            t.z = fmaxf(t.z, 0.f); t.w = fmaxf(t.w, 0.f);
          }
          *reinterpret_cast<float4*>(Y + (size_t)(jb * JT + j) * NN + n0) = t;
        }
      } else {
#pragma unroll
        for (int i = 0; i < 4; ++i) {
          float* yp = Y + (size_t)(n0 + i) * J + jb * JT;
#pragma unroll
          for (int j = 0; j < JT; j += 4) {
            float4 t = {acc[i][j], acc[i][j + 1], acc[i][j + 2], acc[i][j + 3]};
            if (RELU) {
              t.x = fmaxf(t.x, 0.f); t.y = fmaxf(t.y, 0.f);
              t.z = fmaxf(t.z, 0.f); t.w = fmaxf(t.w, 0.f);
            }
            *reinterpret_cast<float4*>(yp + j) = t;
          }
        }
      }
    }
  }
}

// ---------------- aggregation: scalar CSR fetch + 8-deep gather MLP ---------

template <int JC, bool RELU>
__global__ __launch_bounds__(256) void k_agg(const float* __restrict__ p,
                                             const float* __restrict__ q,
                                             const float* __restrict__ bl,
                                             const int* __restrict__ deg,
                                             const int* __restrict__ start,
                                             const int* __restrict__ csr_src,
                                             float* __restrict__ outp) {
  int lane = threadIdx.x & 63;
  int wid  = (blockIdx.x * blockDim.x + threadIdx.x) >> 6;
  int nw   = (gridDim.x * blockDim.x) >> 6;
  bool jl = lane < JC;
  int lidx = jl ? lane : 0;  // clamped feature index for idle lanes
  for (int node = wid; node < NN; node += nw) {
    int d  = __builtin_amdgcn_readfirstlane(deg[node]);
    int st = __builtin_amdgcn_readfirstlane(start[node]);
    float a0 = 0.f, a1 = 0.f, a2 = 0.f, a3 = 0.f;
    float a4 = 0.f, a5 = 0.f, a6 = 0.f, a7 = 0.f;
    int t = 0;
    for (; t + 8 <= d; t += 8) {
      int s0 = __builtin_amdgcn_readfirstlane(csr_src[st + t + 0]);
      int s1 = __builtin_amdgcn_readfirstlane(csr_src[st + t + 1]);
      int s2 = __builtin_amdgcn_readfirstlane(csr_src[st + t + 2]);
      int s3 = __builtin_amdgcn_readfirstlane(csr_src[st + t + 3]);
      int s4 = __builtin_amdgcn_readfirstlane(csr_src[st + t + 4]);
      int s5 = __builtin_amdgcn_readfirstlane(csr_src[st + t + 5]);
      int s6 = __builtin_amdgcn_readfirstlane(csr_src[st + t + 6]);
      int s7 = __builtin_amdgcn_readfirstlane(csr_src[st + t + 7]);
      a0 += p[(size_t)s0 * JC + lidx];
      a1 += p[(size_t)s1 * JC + lidx];
      a2 += p[(size_t)s2 * JC + lidx];
      a3 += p[(size_t)s3 * JC + lidx];
      a4 += p[(size_t)s4 * JC + lidx];
      a5 += p[(size_t)s5 * JC + lidx];
      a6 += p[(size_t)s6 * JC + lidx];
      a7 += p[(size_t)s7 * JC + lidx];
    }
    if (t + 4 <= d) {
      int s0 = __builtin_amdgcn_readfirstlane(csr_src[st + t + 0]);
      int s1 = __builtin_amdgcn_readfirstlane(csr_src[st + t + 1]);
      int s2 = __builtin_amdgcn_readfirstlane(csr_src[st + t + 2]);
      int s3 = __builtin_amdgcn_readfirstlane(csr_src[st + t + 3]);
      a0 += p[(size_t)s0 * JC + lidx];
      a1 += p[(size_t)s1 * JC + lidx];
      a2 += p[(size_t)s2 * JC + lidx];
      a3 += p[(size_t)s3 * JC + lidx];
      t += 4;
    }
    for (; t < d; ++t) {
      int s = __builtin_amdgcn_readfirstlane(csr_src[st + t]);
      a0 += p[(size_t)s * JC + lidx];
    }
    float acc = ((a0 + a1) + (a2 + a3)) + ((a4 + a5) + (a6 + a7));
    float mean = acc / fmaxf((float)d, 1.0f);
    float v = 0.f;
    if (jl) v = mean + bl[lidx] + q[(size_t)node * JC + lidx];
    float ss = v * v;
#pragma unroll
    for (int off = 32; off > 0; off >>= 1) ss += __shfl_xor(ss, off, 64);
    v = v / fmaxf(sqrtf(ss), 1e-12f);
    if (RELU) v = fmaxf(v, 0.f);
    if (jl) outp[(size_t)node * JC + lidx] = v;
  }
}

// ---------------- launch ----------------------------------------------------

static inline size_t align256(size_t x) { return (x + 255) & ~(size_t)255; }

extern "C" void kernel_launch(void* const* d_in, const int* in_sizes, int n_in,
                              void* d_out, int out_size, void* d_ws, size_t ws_size,
                              hipStream_t stream) {
  const float* x    = (const float*)d_in[0];
  const int*   ei   = (const int*)d_in[1];
  const float* Wl1  = (const float*)d_in[2];
  const float* bl1  = (const float*)d_in[3];
  const float* Wr1  = (const float*)d_in[4];
  const float* Wlin = (const float*)d_in[5];
  const float* blin = (const float*)d_in[6];
  const float* Wl2  = (const float*)d_in[7];
  const float* bl2  = (const float*)d_in[8];
  const float* Wr2  = (const float*)d_in[9];
  float* out = (float*)d_out;

  char* w = (char*)d_ws;
  size_t off = 0;
  int* deg     = (int*)(w + off); off += align256((size_t)NN * 4);
  int* start   = (int*)(w + off); off += align256((size_t)NN * 4);
  int* counter = (int*)(w + off); off += 256;
  int* csr_src = (int*)(w + off); off += align256((size_t)NE * 4);
  float* xt    = (float*)(w + off); off += align256((size_t)F * NN * 4);     // 25.6 MB
  float* bufP  = (float*)(w + off); off += align256((size_t)2 * NN * H * 4); // 25.6 MB
  float* hidden= (float*)(w + off); off += align256((size_t)NN * H * 4);     // 12.8 MB

  // liveness overlays:
  int*   hist    = (int*)bufP;                 // CSR build only (dead before gemm1)
  float* p1      = bufP;                       // gemm1 -> agg1
  float* q1      = bufP + (size_t)NN * H;      // gemm1 -> agg1
  float* hiddenT = bufP;                       // tr(hidden) -> lin1 (p1 dead)
  float* hT      = bufP + (size_t)NN * H;      // lin1 -> gemm2 (q1 dead)
  float* p2      = xt;                         // gemm2 -> agg2 (xt dead)
  float* q2      = xt + (size_t)NN * C;

  hipMemsetAsync(counter, 0, 4, stream);

  const int T = 256;
  // CSR build: counting sort, no device atomics per edge
  k_hist <<<NB_BK * NCH, T, 0, stream>>>(ei, hist);
  k_scan <<<196, T, 0, stream>>>(hist, deg, start, counter);
  k_fill2<<<NB_BK * NCH, T, 0, stream>>>(ei, hist, start, csr_src);

  // xt = x^T  [F][NN]
  k_tr<<<782 * (F / 64), T, 0, stream>>>(x, xt, F);

  // p1 = x@Wl1, q1 = x@Wr1  (one launch, 392 wave-items)
  k_gemm<F, 0, H, 16, 2, false, false, false><<<392, T, 0, stream>>>(
      xt, nullptr, Wl1, Wr1, nullptr, p1, q1);

  // hidden = relu(l2norm(mean_agg(p1) + bl1 + q1))
  k_agg<H, true><<<2048, T, 0, stream>>>(p1, q1, bl1, deg, start, csr_src, hidden);

  // hiddenT = hidden^T [H][NN]  (p1 region dead)
  k_tr<<<782 * (H / 64), T, 0, stream>>>(hidden, hiddenT, H);

  // hT = relu([x, hidden] @ Wlin + blin)^T  [H][NN]
  k_gemm<F, H, H, 16, 1, true, true, true><<<196, T, 0, stream>>>(
      xt, hiddenT, Wlin, nullptr, blin, hT, nullptr);

  // p2 = h@Wl2, q2 = h@Wr2  (xt dead -> reuse region)
  k_gemm<H, 0, C, 20, 2, false, false, false><<<196, T, 0, stream>>>(
      hT, nullptr, Wl2, Wr2, nullptr, p2, q2);

  // out = l2norm(mean_agg(p2) + bl2 + q2)
  k_agg<C, false><<<2048, T, 0, stream>>>(p2, q2, bl2, deg, start, csr_src, out);
}

// Round 6
// 277.950 us; speedup vs baseline: 3.6377x; 1.1810x over previous
//
#include <hip/hip_runtime.h>

static constexpr int NN = 50000;   // nodes
static constexpr int NE = 800000;  // edges
static constexpr int F  = 128;     // input features
static constexpr int H  = 64;      // hidden
static constexpr int C  = 40;      // classes

static constexpr int NB_BK = 8;          // node buckets (XCD-aligned)
static constexpr int NCH   = 32;         // edge chunks
static constexpr int ECH   = NE / NCH;   // 25000 edges per chunk
static constexpr int NBK   = NN / NB_BK; // 6250 nodes per bucket

// ---------------- CSR build: XCD-aligned counting sort ----------------------

__global__ __launch_bounds__(256) void k_hist(const int* __restrict__ ei,
                                              int* __restrict__ hist) {
  __shared__ int cnt[NBK];
  int i = blockIdx.x & 7;
  int j = blockIdx.x >> 3;
  for (int t = threadIdx.x; t < NBK; t += 256) cnt[t] = 0;
  __syncthreads();
  int lo = i * NBK;
  const int* dst = ei + NE + j * ECH;
  for (int base = threadIdx.x * 4; base < ECH; base += 256 * 4) {
    int4 d4 = *reinterpret_cast<const int4*>(dst + base);
    if ((unsigned)(d4.x - lo) < (unsigned)NBK) atomicAdd(&cnt[d4.x - lo], 1);
    if ((unsigned)(d4.y - lo) < (unsigned)NBK) atomicAdd(&cnt[d4.y - lo], 1);
    if ((unsigned)(d4.z - lo) < (unsigned)NBK) atomicAdd(&cnt[d4.z - lo], 1);
    if ((unsigned)(d4.w - lo) < (unsigned)NBK) atomicAdd(&cnt[d4.w - lo], 1);
  }
  __syncthreads();
  int* hrow = hist + (size_t)j * NN + lo;
  for (int t = threadIdx.x; t < NBK; t += 256) hrow[t] = cnt[t];
}

__global__ __launch_bounds__(256) void k_scan(int* __restrict__ hist,
                                              int* __restrict__ deg,
                                              int* __restrict__ start,
                                              int* __restrict__ counter) {
  int lane = threadIdx.x & 63;
  int wid  = (blockIdx.x * blockDim.x + threadIdx.x) >> 6;
  int nw   = (gridDim.x * blockDim.x) >> 6;
  int nchunks = (NN + 63) >> 6;
  for (int c = wid; c < nchunks; c += nw) {
    int n = (c << 6) + lane;
    int d = 0;
    if (n < NN) {
      int run = 0;
#pragma unroll
      for (int j = 0; j < NCH; ++j) {
        int v = hist[(size_t)j * NN + n];
        hist[(size_t)j * NN + n] = run;
        run += v;
      }
      d = run;
    }
    int inc = d;
#pragma unroll
    for (int off = 1; off < 64; off <<= 1) {
      int t = __shfl_up(inc, off, 64);
      if (lane >= off) inc += t;
    }
    int total = __shfl(inc, 63, 64);
    int base = 0;
    if (lane == 63) base = atomicAdd(counter, total);
    base = __shfl(base, 63, 64);
    if (n < NN) {
      deg[n]   = d;
      start[n] = base + inc - d;
    }
  }
}

__global__ __launch_bounds__(256) void k_fill2(const int* __restrict__ ei,
                                               const int* __restrict__ hist,
                                               const int* __restrict__ start,
                                               int* __restrict__ csr_src) {
  __shared__ int fill[NBK];
  int i = blockIdx.x & 7;
  int j = blockIdx.x >> 3;
  int lo = i * NBK;
  const int* hrow = hist + (size_t)j * NN + lo;
  for (int t = threadIdx.x; t < NBK; t += 256) fill[t] = start[lo + t] + hrow[t];
  __syncthreads();
  const int* srcp = ei + j * ECH;
  const int* dstp = ei + NE + j * ECH;
  for (int base = threadIdx.x * 4; base < ECH; base += 256 * 4) {
    int4 s4 = *reinterpret_cast<const int4*>(srcp + base);
    int4 d4 = *reinterpret_cast<const int4*>(dstp + base);
    if ((unsigned)(d4.x - lo) < (unsigned)NBK) { int p = atomicAdd(&fill[d4.x - lo], 1); csr_src[p] = s4.x; }
    if ((unsigned)(d4.y - lo) < (unsigned)NBK) { int p = atomicAdd(&fill[d4.y - lo], 1); csr_src[p] = s4.y; }
    if ((unsigned)(d4.z - lo) < (unsigned)NBK) { int p = atomicAdd(&fill[d4.z - lo], 1); csr_src[p] = s4.z; }
    if ((unsigned)(d4.w - lo) < (unsigned)NBK) { int p = atomicAdd(&fill[d4.w - lo], 1); csr_src[p] = s4.w; }
  }
}

// ---------------- dense MM: block = 64-node tile staged in LDS --------------
// LDS layout [k][node] with rotation swizzle (node + k/4)&63: transposing
// ds_writes and compute ds_reads are both bank-conflict-free. Inputs read
// row-major directly from global (coalesced float4, each element fetched
// once). 4 waves split (mat x j-range); lane = node; weights via wave-uniform
// s_load; acc in VGPRs; coalesced float4 row-major stores.

template <int K1, int K2, int J, int JT, int NMAT, bool BIAS, bool RELU>
__global__ __launch_bounds__(256) void k_mm(const float* __restrict__ X1,
                                            const float* __restrict__ X2,
                                            const float* __restrict__ W0,
                                            const float* __restrict__ W1,
                                            const float* __restrict__ bias,
                                            float* __restrict__ Y0,
                                            float* __restrict__ Y1) {
  constexpr int K = K1 + K2;
  __shared__ float xs[K * 64];
  int n0 = blockIdx.x << 6;
  {
    constexpr int RPT = K1 / 4;  // float4 per row
    for (int i = threadIdx.x; i < 64 * RPT; i += 256) {
      int node = i / RPT, kq = i % RPT;
      int nn = n0 + node; if (nn > NN - 1) nn = NN - 1;
      float4 v = *reinterpret_cast<const float4*>(X1 + (size_t)nn * K1 + kq * 4);
      int sw = (node + kq) & 63;
      xs[(kq * 4 + 0) * 64 + sw] = v.x;
      xs[(kq * 4 + 1) * 64 + sw] = v.y;
      xs[(kq * 4 + 2) * 64 + sw] = v.z;
      xs[(kq * 4 + 3) * 64 + sw] = v.w;
    }
  }
  if constexpr (K2 > 0) {
    constexpr int RPT = K2 / 4;
    for (int i = threadIdx.x; i < 64 * RPT; i += 256) {
      int node = i / RPT, kq = i % RPT;
      int nn = n0 + node; if (nn > NN - 1) nn = NN - 1;
      float4 v = *reinterpret_cast<const float4*>(X2 + (size_t)nn * K2 + kq * 4);
      int k0 = K1 + kq * 4;
      int sw = (node + (k0 >> 2)) & 63;
      xs[(k0 + 0) * 64 + sw] = v.x;
      xs[(k0 + 1) * 64 + sw] = v.y;
      xs[(k0 + 2) * 64 + sw] = v.z;
      xs[(k0 + 3) * 64 + sw] = v.w;
    }
  }
  __syncthreads();

  int lane = threadIdx.x & 63;
  int wv   = __builtin_amdgcn_readfirstlane(threadIdx.x >> 6);
  int mat  = (NMAT == 2) ? (wv >> 1) : 0;
  int jh   = (NMAT == 2) ? (wv & 1) : wv;
  const float* W = (NMAT == 2) ? (mat ? W1 : W0) : W0;
  float*       Y = (NMAT == 2) ? (mat ? Y1 : Y0) : Y0;
  int jb = jh * JT;

  float acc[JT];
#pragma unroll
  for (int j = 0; j < JT; ++j) acc[j] = BIAS ? bias[jb + j] : 0.f;

#pragma unroll 4
  for (int k = 0; k < K; ++k) {
    float xv = xs[k * 64 + ((lane + (k >> 2)) & 63)];
    const float* wr = W + k * J + jb;
#pragma unroll
    for (int j = 0; j < JT; ++j) acc[j] += xv * wr[j];
  }

  int node = n0 + lane;
  if (node < NN) {
    float* yp = Y + (size_t)node * J + jb;
#pragma unroll
    for (int j = 0; j < JT; j += 4) {
      float4 t = {acc[j], acc[j + 1], acc[j + 2], acc[j + 3]};
      if (RELU) {
        t.x = fmaxf(t.x, 0.f); t.y = fmaxf(t.y, 0.f);
        t.z = fmaxf(t.z, 0.f); t.w = fmaxf(t.w, 0.f);
      }
      *reinterpret_cast<float4*>(yp + j) = t;
    }
  }
}

// ---------------- aggregation: scalar CSR fetch + 8-deep gather MLP ---------

template <int JC, bool RELU>
__global__ __launch_bounds__(256) void k_agg(const float* __restrict__ p,
                                             const float* __restrict__ q,
                                             const float* __restrict__ bl,
                                             const int* __restrict__ deg,
                                             const int* __restrict__ start,
                                             const int* __restrict__ csr_src,
                                             float* __restrict__ outp) {
  int lane = threadIdx.x & 63;
  int wid  = (blockIdx.x * blockDim.x + threadIdx.x) >> 6;
  int nw   = (gridDim.x * blockDim.x) >> 6;
  bool jl = lane < JC;
  int lidx = jl ? lane : 0;
  for (int node = wid; node < NN; node += nw) {
    int d  = __builtin_amdgcn_readfirstlane(deg[node]);
    int st = __builtin_amdgcn_readfirstlane(start[node]);
    float a0 = 0.f, a1 = 0.f, a2 = 0.f, a3 = 0.f;
    float a4 = 0.f, a5 = 0.f, a6 = 0.f, a7 = 0.f;
    int t = 0;
    for (; t + 8 <= d; t += 8) {
      int s0 = __builtin_amdgcn_readfirstlane(csr_src[st + t + 0]);
      int s1 = __builtin_amdgcn_readfirstlane(csr_src[st + t + 1]);
      int s2 = __builtin_amdgcn_readfirstlane(csr_src[st + t + 2]);
      int s3 = __builtin_amdgcn_readfirstlane(csr_src[st + t + 3]);
      int s4 = __builtin_amdgcn_readfirstlane(csr_src[st + t + 4]);
      int s5 = __builtin_amdgcn_readfirstlane(csr_src[st + t + 5]);
      int s6 = __builtin_amdgcn_readfirstlane(csr_src[st + t + 6]);
      int s7 = __builtin_amdgcn_readfirstlane(csr_src[st + t + 7]);
      a0 += p[(size_t)s0 * JC + lidx];
      a1 += p[(size_t)s1 * JC + lidx];
      a2 += p[(size_t)s2 * JC + lidx];
      a3 += p[(size_t)s3 * JC + lidx];
      a4 += p[(size_t)s4 * JC + lidx];
      a5 += p[(size_t)s5 * JC + lidx];
      a6 += p[(size_t)s6 * JC + lidx];
      a7 += p[(size_t)s7 * JC + lidx];
    }
    if (t + 4 <= d) {
      int s0 = __builtin_amdgcn_readfirstlane(csr_src[st + t + 0]);
      int s1 = __builtin_amdgcn_readfirstlane(csr_src[st + t + 1]);
      int s2 = __builtin_amdgcn_readfirstlane(csr_src[st + t + 2]);
      int s3 = __builtin_amdgcn_readfirstlane(csr_src[st + t + 3]);
      a0 += p[(size_t)s0 * JC + lidx];
      a1 += p[(size_t)s1 * JC + lidx];
      a2 += p[(size_t)s2 * JC + lidx];
      a3 += p[(size_t)s3 * JC + lidx];
      t += 4;
    }
    for (; t < d; ++t) {
      int s = __builtin_amdgcn_readfirstlane(csr_src[st + t]);
      a0 += p[(size_t)s * JC + lidx];
    }
    float acc = ((a0 + a1) + (a2 + a3)) + ((a4 + a5) + (a6 + a7));
    float mean = acc / fmaxf((float)d, 1.0f);
    float v = 0.f;
    if (jl) v = mean + bl[lidx] + q[(size_t)node * JC + lidx];
    float ss = v * v;
#pragma unroll
    for (int off = 32; off > 0; off >>= 1) ss += __shfl_xor(ss, off, 64);
    v = v / fmaxf(sqrtf(ss), 1e-12f);
    if (RELU) v = fmaxf(v, 0.f);
    if (jl) outp[(size_t)node * JC + lidx] = v;
  }
}

// ---------------- launch ----------------------------------------------------

static inline size_t align256(size_t x) { return (x + 255) & ~(size_t)255; }

extern "C" void kernel_launch(void* const* d_in, const int* in_sizes, int n_in,
                              void* d_out, int out_size, void* d_ws, size_t ws_size,
                              hipStream_t stream) {
  const float* x    = (const float*)d_in[0];
  const int*   ei   = (const int*)d_in[1];
  const float* Wl1  = (const float*)d_in[2];
  const float* bl1  = (const float*)d_in[3];
  const float* Wr1  = (const float*)d_in[4];
  const float* Wlin = (const float*)d_in[5];
  const float* blin = (const float*)d_in[6];
  const float* Wl2  = (const float*)d_in[7];
  const float* bl2  = (const float*)d_in[8];
  const float* Wr2  = (const float*)d_in[9];
  float* out = (float*)d_out;

  char* w = (char*)d_ws;
  size_t off = 0;
  int* deg     = (int*)(w + off); off += align256((size_t)NN * 4);
  int* start   = (int*)(w + off); off += align256((size_t)NN * 4);
  int* counter = (int*)(w + off); off += 256;
  int* csr_src = (int*)(w + off); off += align256((size_t)NE * 4);
  float* bufP  = (float*)(w + off); off += align256((size_t)2 * NN * H * 4);  // 25.6 MB
  float* hidden= (float*)(w + off); off += align256((size_t)NN * H * 4);      // 12.8 MB
  float* bufQ  = (float*)(w + off); off += align256((size_t)2 * NN * C * 4);  // 16 MB

  // liveness overlays:
  int*   hist = (int*)bufP;               // CSR build only (dead before gemm1)
  float* p1   = bufP;                     // gemm1 -> agg1
  float* q1   = bufP + (size_t)NN * H;    // gemm1 -> agg1
  float* h    = bufP;                     // lin1 -> gemm2 (p1/q1 dead)
  float* p2   = bufQ;                     // gemm2 -> agg2
  float* q2   = bufQ + (size_t)NN * C;

  hipMemsetAsync(counter, 0, 4, stream);

  const int T = 256;
  const int NTILE = (NN + 63) / 64;  // 782

  // CSR build: counting sort, no device atomics per edge
  k_hist <<<NB_BK * NCH, T, 0, stream>>>(ei, hist);
  k_scan <<<196, T, 0, stream>>>(hist, deg, start, counter);
  k_fill2<<<NB_BK * NCH, T, 0, stream>>>(ei, hist, start, csr_src);

  // p1 = x@Wl1, q1 = x@Wr1   (one pass over x, LDS-tiled)
  k_mm<F, 0, H, 32, 2, false, false><<<NTILE, T, 0, stream>>>(
      x, nullptr, Wl1, Wr1, nullptr, p1, q1);

  // hidden = relu(l2norm(mean_agg(p1) + bl1 + q1))
  k_agg<H, true><<<2048, T, 0, stream>>>(p1, q1, bl1, deg, start, csr_src, hidden);

  // h = relu([x, hidden] @ Wlin + blin)   (p1/q1 dead -> h overlays bufP)
  k_mm<F, H, H, 16, 1, true, true><<<NTILE, T, 0, stream>>>(
      x, hidden, Wlin, nullptr, blin, h, nullptr);

  // p2 = h@Wl2, q2 = h@Wr2
  k_mm<H, 0, C, 20, 2, false, false><<<NTILE, T, 0, stream>>>(
      h, nullptr, Wl2, Wr2, nullptr, p2, q2);

  // out = l2norm(mean_agg(p2) + bl2 + q2)
  k_agg<C, false><<<2048, T, 0, stream>>>(p2, q2, bl2, deg, start, csr_src, out);
}